// Round 14
// baseline (111.705 us; speedup 1.0000x reference)
//
#include <hip/hip_runtime.h>

// ---------------------------------------------------------------------------
// TransNetSweepingExplRhs — R14 = R13 + intra-block K-split waves (LDS -25%).
//   h = x@W_in^T + b_in ; th = tanh(h); r1u = h + 0.1 b1
//   Q_i = I/11 - (0.01/121) W_i^T W_i   (symmetric);  A_i = W_i@Q_i
//   b1v = 11 th + 0.1 (r1u@W1)
//   r2u = r1u + 0.1 b2 - 0.1 NT(b1v, A1)
//   b2v = 10 th + [b1v | 0.1 r2u] @ [Q1 ; W2^T]   (K=2048)
//   y2u = r2u - 0.1 NT(b2v, A2)
//   logits = NT(y2u, Wout) + bout ; out = softmax
// GEMM: 64x64 tile, 4 waves; wave w = (ksw=w>>1, wc=w&1) owns a 64x32
// wave tile restricted to K-slice ksw (reads/MFMA 0.75 vs 1.0 -> LDS
// traffic 24KB/kt vs 32). One 16KB LDS reduction + guarded epilogue merges
// ks-halves (once per GEMM). Superphase pipeline (4 bufs, 1 barrier +
// vmcnt(0)/2kt), rotation swizzle, setprio, D5 L2-fit map: unchanged (R12/13).
// ---------------------------------------------------------------------------

typedef short bf16x8 __attribute__((ext_vector_type(8)));
typedef float f32x4 __attribute__((ext_vector_type(4)));

#define M1 1048576

__device__ __forceinline__ unsigned short f2b(float f) {
  union { float f; unsigned int u; } v; v.f = f;
  unsigned int u = v.u;
  return (unsigned short)((u + 0x7FFFu + ((u >> 16) & 1u)) >> 16);
}

__device__ __forceinline__ void gload16(const void* g, void* l) {
  __builtin_amdgcn_global_load_lds(
      (const __attribute__((address_space(1))) unsigned int*)g,
      (__attribute__((address_space(3))) unsigned int*)l, 16, 0, 0);
}

// C[m,n] = sum_k A[m,k]*B[n,k]; tile 64x64 at (bx,by); K = NKT*64, NKT even.
// Waves: ksw = wid>>1 (K-slice), wc = wid&1 (col half). Wave tile 64x32,
// acc[4][2] (32 f32). 8-chunk rotation swizzle both sides.
template <int MODE, int NKT>
__device__ __forceinline__ void gemm64(
    const unsigned short* __restrict__ A, int lda,
    const unsigned short* __restrict__ B, int ldb,
    int bx, int by,
    const float* bias0, const float* bias1, const float* src0,
    float* dstf0, float* dstf1,
    unsigned short* dstbf, int ldc, unsigned short* dstbf2,
    short (*As)[4096], short (*Bs)[4096]) {
  const int tid = threadIdx.x;
  const int lane = tid & 63;
  const int wid = tid >> 6;
  const int ksw = wid >> 1;  // K-slice 0/1
  const int wc = wid & 1;    // col half
  const int m0 = bx * 64;
  const int n0 = by * 64;
  const int l15 = lane & 15;
  const int kb = lane >> 4;

  const int sr = tid >> 3;
  const int sg = ((tid & 7) - sr) & 7;
  const unsigned short* Asrc = A + (size_t)(m0 + sr) * lda + sg * 8;
  const unsigned short* Bsrc = B + (size_t)(n0 + sr) * ldb + sg * 8;
  const size_t a32 = (size_t)32 * lda;
  const size_t b32 = (size_t)32 * ldb;
  const int o0 = tid * 8;
  const int o1 = 2048 + tid * 8;

  f32x4 acc[4][2];
#pragma unroll
  for (int f = 0; f < 4; ++f)
#pragma unroll
    for (int g = 0; g < 2; ++g) acc[f][g] = (f32x4){0.f, 0.f, 0.f, 0.f};

#define STG(kt, buf)                                  \
  do {                                                \
    gload16(Asrc + (kt) * 64, &As[(buf)][o0]);        \
    gload16(Asrc + a32 + (kt) * 64, &As[(buf)][o1]);  \
    gload16(Bsrc + (kt) * 64, &Bs[(buf)][o0]);        \
    gload16(Bsrc + b32 + (kt) * 64, &Bs[(buf)][o1]);  \
  } while (0)

#define CMP(kt)                                                                \
  do {                                                                         \
    const int cb = (kt) & 3;                                                   \
    bf16x8 av[4], bv[2];                                                       \
    _Pragma("unroll") for (int f = 0; f < 4; ++f) {                            \
      const int ra = f * 16 + l15;                                             \
      const int qa = (ksw * 4 + kb + l15) & 7;                                 \
      av[f] = *reinterpret_cast<const bf16x8*>(&As[cb][ra * 64 + qa * 8]);     \
    }                                                                          \
    _Pragma("unroll") for (int g = 0; g < 2; ++g) {                            \
      const int rb = wc * 32 + g * 16 + l15;                                   \
      const int qb2 = (ksw * 4 + kb + l15) & 7;                                \
      bv[g] = *reinterpret_cast<const bf16x8*>(&Bs[cb][rb * 64 + qb2 * 8]);    \
    }                                                                          \
    _Pragma("unroll") for (int f = 0; f < 4; ++f)                              \
        _Pragma("unroll") for (int g = 0; g < 2; ++g)                          \
            acc[f][g] = __builtin_amdgcn_mfma_f32_16x16x32_bf16(               \
                av[f], bv[g], acc[f][g], 0, 0, 0);                             \
  } while (0)

  // prologue: stage pair 0 only (kt 0,1)
  STG(0, 0);
  STG(1, 1);

#pragma unroll
  for (int s = 0; s < NKT / 2; ++s) {
    const int k0 = 2 * s;
    asm volatile("s_waitcnt vmcnt(0)" ::: "memory");
    __builtin_amdgcn_sched_barrier(0);
    __builtin_amdgcn_s_barrier();
    __builtin_amdgcn_sched_barrier(0);
    if (k0 + 2 < NKT) STG(k0 + 2, (k0 + 2) & 3);
    if (k0 + 3 < NKT) STG(k0 + 3, (k0 + 3) & 3);
    __builtin_amdgcn_s_setprio(1);
    CMP(k0);
    CMP(k0 + 1);
    __builtin_amdgcn_s_setprio(0);
  }
#undef STG
#undef CMP

  // merge ks-halves: waves ksw=1 dump acc to LDS, waves ksw=0 add.
  f32x4* fbuf = reinterpret_cast<f32x4*>(&As[0][0]);  // 16 KB
  __syncthreads();
  if (ksw == 1) {
#pragma unroll
    for (int f = 0; f < 4; ++f)
#pragma unroll
      for (int g = 0; g < 2; ++g)
        fbuf[wc * 512 + (f * 2 + g) * 64 + lane] = acc[f][g];
  }
  __syncthreads();
  if (ksw == 0) {
#pragma unroll
    for (int f = 0; f < 4; ++f)
#pragma unroll
      for (int g = 0; g < 2; ++g)
        acc[f][g] += fbuf[wc * 512 + (f * 2 + g) * 64 + lane];

    // epilogue (waves 0,1 cover all 64 rows x their 32-col half)
    // C/D layout: col = lane&15, row = (lane>>4)*4 + j within each 16x16
#pragma unroll
    for (int f = 0; f < 4; ++f) {
#pragma unroll
      for (int g = 0; g < 2; ++g) {
#pragma unroll
        for (int j = 0; j < 4; ++j) {
          int m = m0 + f * 16 + kb * 4 + j;
          int n = n0 + wc * 32 + g * 16 + l15;
          size_t fidx = (size_t)m * 1024 + n;
          size_t cidx = (size_t)m * ldc + n;
          float v = acc[f][g][j];
          if (MODE == 0) {                  // plain bf16 (A1/A2)
            dstbf[cidx] = f2b(v);
          } else if (MODE == 1) {           // h-stage
            float h = v + bias0[n];
            float thv = tanhf(h);
            float r = h + 0.1f * bias1[n];
            dstf0[fidx] = r;
            dstf1[fidx] = thv;
            dstbf[cidx] = f2b(r);
          } else if (MODE == 2) {           // b1v = 11 th + 0.1 c1 -> zcat lo
            dstbf[cidx] = f2b(11.0f * src0[fidx] + 0.1f * v);
          } else if (MODE == 4) {           // r2u; store 0.1*r2u bf16 -> zcat hi
            float r = src0[fidx] + 0.1f * bias0[n] - 0.1f * v;
            dstf0[fidx] = r;
            dstbf[cidx] = f2b(0.1f * r);
          } else if (MODE == 5) {           // b2v = 10 th + v
            dstbf[cidx] = f2b(10.0f * src0[fidx] + v);
          } else if (MODE == 7) {           // y2u = r2u - 0.1 v
            dstbf[cidx] = f2b(src0[fidx] - 0.1f * v);
          } else if (MODE == 8) {           // logits
            dstf0[fidx] = v + bias0[n];
          } else {                          // MODE 9: Q = I/11 - (0.01/121) P
            float q = (m == n ? (1.0f / 11.0f) : 0.0f) - (0.01f / 121.0f) * v;
            unsigned short qq = f2b(q);
            dstbf[cidx] = qq;
            if (dstbf2) dstbf2[(size_t)m * 2048 + n] = qq;  // bcat lo (Q1)
          }
        }
      }
    }
  }
}

__device__ __forceinline__ void map512(int b, int& bx, int& by) {
  bx = ((b & 7) << 2) | ((b >> 3) & 3);  // 0..31
  by = b >> 5;                           // 0..15
}
__device__ __forceinline__ void map256(int r, int& bx, int& by) {
  bx = ((r & 7) << 1) | ((r >> 3) & 1);  // 0..15
  by = (r >> 4) & 15;                    // 0..15
}
// D5-only: 8bx x 8by per XCD -> per-XCD footprint A 2MB + B 2MB (K=2048)
__device__ __forceinline__ void map512k2(int b, int& bx, int& by) {
  const int x = b & 7;
  const int j = b >> 3;
  bx = ((x & 3) << 3) | (j & 7);
  by = ((x >> 2) << 3) | (j >> 3);
}

// D2: G0 (h-stage, blocks 0..511) + QG (Q1,Q2, blocks 512..1023)
__global__ __launch_bounds__(256) void k_D2(
    const unsigned short* __restrict__ xb, const unsigned short* __restrict__ winb,
    const unsigned short* __restrict__ wtb,
    const float* __restrict__ b_in, const float* __restrict__ b1,
    float* __restrict__ r1u, float* __restrict__ th,
    unsigned short* __restrict__ zb0, unsigned short* __restrict__ qb,
    unsigned short* __restrict__ bcat) {
  __shared__ short As[4][4096];
  __shared__ short Bs[4][4096];
  const int b = blockIdx.x;
  int bx, by;
  if (b < 512) {
    map512(b, bx, by);
    gemm64<1, 16>(xb, 1024, winb, 1024, bx, by, b_in, b1, nullptr,
                  r1u, th, zb0, 1024, nullptr, As, Bs);
  } else {
    int r = b - 512;
    const int z = r >> 8;
    map256(r & 255, bx, by);
    const unsigned short* wt = wtb + (size_t)z * M1;
    gemm64<9, 16>(wt, 1024, wt, 1024, bx, by, nullptr, nullptr, nullptr,
                  nullptr, nullptr, qb + (size_t)z * M1, 1024,
                  z == 0 ? bcat : nullptr, As, Bs);
  }
}

// D3: A1 (0..255), A2 (256..511), G1/b1v (512..1023)
__global__ __launch_bounds__(256) void k_D3(
    const unsigned short* __restrict__ wb, const unsigned short* __restrict__ qb,
    const unsigned short* __restrict__ zb0, const unsigned short* __restrict__ wtb,
    const float* __restrict__ th,
    unsigned short* __restrict__ a1b, unsigned short* __restrict__ a2b,
    unsigned short* __restrict__ zcat) {
  __shared__ short As[4][4096];
  __shared__ short Bs[4][4096];
  const int b = blockIdx.x;
  int bx, by;
  if (b < 512) {
    const int z = b >> 8;
    map256(b & 255, bx, by);
    gemm64<0, 16>(wb + (size_t)z * M1, 1024, qb + (size_t)z * M1, 1024, bx, by,
                  nullptr, nullptr, nullptr, nullptr, nullptr,
                  z == 0 ? a1b : a2b, 1024, nullptr, As, Bs);
  } else {
    map512(b - 512, bx, by);
    gemm64<2, 16>(zb0, 1024, wtb, 1024, bx, by, nullptr, nullptr, th,
                  nullptr, nullptr, zcat, 2048, nullptr, As, Bs);
  }
}

// D4: r2u = r1u + 0.1 b2 - 0.1 NT(b1v, A1)
__global__ __launch_bounds__(256) void k_D4(
    const unsigned short* __restrict__ zcat, const unsigned short* __restrict__ a1b,
    const float* __restrict__ b2, const float* __restrict__ r1u,
    float* __restrict__ r2u, unsigned short* __restrict__ zcat_hi) {
  __shared__ short As[4][4096];
  __shared__ short Bs[4][4096];
  int bx, by;
  map512(blockIdx.x, bx, by);
  gemm64<4, 16>(zcat, 2048, a1b, 1024, bx, by, b2, nullptr, r1u,
                r2u, nullptr, zcat_hi, 2048, nullptr, As, Bs);
}

// D5: b2v = 10 th + [b1v | 0.1 r2u] @ bcat  (K=2048)
__global__ __launch_bounds__(256) void k_D5(
    const unsigned short* __restrict__ zcat, const unsigned short* __restrict__ bcat,
    const float* __restrict__ th, unsigned short* __restrict__ zb2) {
  __shared__ short As[4][4096];
  __shared__ short Bs[4][4096];
  int bx, by;
  map512k2(blockIdx.x, bx, by);
  gemm64<5, 32>(zcat, 2048, bcat, 2048, bx, by, nullptr, nullptr, th,
                nullptr, nullptr, zb2, 1024, nullptr, As, Bs);
}

// D6: y2u = r2u - 0.1 NT(b2v, A2)
__global__ __launch_bounds__(256) void k_D6(
    const unsigned short* __restrict__ zb2, const unsigned short* __restrict__ a2b,
    const float* __restrict__ r2u, unsigned short* __restrict__ zb3) {
  __shared__ short As[4][4096];
  __shared__ short Bs[4][4096];
  int bx, by;
  map512(blockIdx.x, bx, by);
  gemm64<7, 16>(zb2, 1024, a2b, 1024, bx, by, nullptr, nullptr, r2u,
                nullptr, nullptr, zb3, 1024, nullptr, As, Bs);
}

// D7: logits = NT(y2u, Wout_pad) + bout
__global__ __launch_bounds__(256) void k_D7(
    const unsigned short* __restrict__ zb3, const unsigned short* __restrict__ woutb,
    const float* __restrict__ boutp, float* __restrict__ lgts) {
  __shared__ short As[4][4096];
  __shared__ short Bs[4][4096];
  int bx, by;
  map512(blockIdx.x, bx, by);
  gemm64<8, 16>(zb3, 1024, woutb, 1024, bx, by, boutp, nullptr, nullptr,
                lgts, nullptr, nullptr, 1024, nullptr, As, Bs);
}

// prep: W1/W2 bf16+transpose (0..2047; W2 also fills bcat hi), x (2048..4095),
// W_in (4096..5119), W_out padded (5120..6143), b_out (6144)
__global__ __launch_bounds__(256) void k_prep(
    const float* __restrict__ x, const float* __restrict__ Win,
    const float* __restrict__ W1, const float* __restrict__ W2,
    const float* __restrict__ Wout, const float* __restrict__ bout,
    unsigned short* __restrict__ xb, unsigned short* __restrict__ winb,
    unsigned short* __restrict__ wb, unsigned short* __restrict__ wtb,
    unsigned short* __restrict__ woutb, float* __restrict__ boutp,
    unsigned short* __restrict__ bcat) {
  __shared__ float tile[32][33];
  const int b = blockIdx.x;
  const int tid = threadIdx.x;
  if (b < 2048) {
    const int isW2 = (b >> 10) & 1;
    const float* W = isW2 ? W2 : W1;
    unsigned short* Wb = wb + ((size_t)isW2 << 20);
    unsigned short* WTb = wtb + ((size_t)isW2 << 20);
    const int rem = b & 1023;
    const int tbx = rem & 31, tby = rem >> 5;
    const int tx = tid & 31, ty = tid >> 5;
#pragma unroll
    for (int i = ty; i < 32; i += 8) {
      float v = W[(size_t)(tby * 32 + i) * 1024 + tbx * 32 + tx];
      tile[i][tx] = v;
      Wb[(size_t)(tby * 32 + i) * 1024 + tbx * 32 + tx] = f2b(v);
    }
    __syncthreads();
#pragma unroll
    for (int i = ty; i < 32; i += 8) {
      unsigned short t2 = f2b(tile[tx][i]);
      int rr = tbx * 32 + i, cc = tby * 32 + tx;
      WTb[(size_t)rr * 1024 + cc] = t2;
      if (isW2) bcat[(size_t)rr * 2048 + 1024 + cc] = t2;  // bcat hi = W2^T
    }
  } else if (b < 4096) {
    int i = (b - 2048) * 256 + tid;
    float4 v = ((const float4*)x)[i];
    ((ushort4*)xb)[i] = (ushort4){f2b(v.x), f2b(v.y), f2b(v.z), f2b(v.w)};
  } else if (b < 5120) {
    int i = (b - 4096) * 256 + tid;
    float4 v = ((const float4*)Win)[i];
    ((ushort4*)winb)[i] = (ushort4){f2b(v.x), f2b(v.y), f2b(v.z), f2b(v.w)};
  } else if (b < 6144) {
    int i = (b - 5120) * 256 + tid;
    ushort4 o = (ushort4){0, 0, 0, 0};
    if ((i >> 8) < 1000) {
      float4 v = ((const float4*)Wout)[i];
      o = (ushort4){f2b(v.x), f2b(v.y), f2b(v.z), f2b(v.w)};
    }
    ((ushort4*)woutb)[i] = o;
  } else {
    for (int j = tid; j < 1024; j += 256) boutp[j] = (j < 1000) ? bout[j] : 0.0f;
  }
}

// row softmax over first 1000 cols of 2048x1024 logits -> 2048x1000
__global__ __launch_bounds__(256) void k_softmax(const float* __restrict__ lg,
                                                 float* __restrict__ out) {
  const int r = blockIdx.x;
  const float4* p4 = (const float4*)(lg + (size_t)r * 1024);
  float* q = out + (size_t)r * 1000;
  const int tid = threadIdx.x;
  const int lane = tid & 63;
  const int w = tid >> 6;
  __shared__ float redm[4];
  __shared__ float reds[4];
  float m = -3.0e38f;
  for (int i = tid; i < 250; i += 256) {
    float4 v = p4[i];
    m = fmaxf(fmaxf(fmaxf(m, v.x), fmaxf(v.y, v.z)), v.w);
  }
#pragma unroll
  for (int o = 32; o > 0; o >>= 1) m = fmaxf(m, __shfl_xor(m, o));
  if (lane == 0) redm[w] = m;
  __syncthreads();
  m = fmaxf(fmaxf(redm[0], redm[1]), fmaxf(redm[2], redm[3]));
  float s = 0.0f;
  for (int i = tid; i < 250; i += 256) {
    float4 v = p4[i];
    float e0 = __expf(v.x - m), e1 = __expf(v.y - m);
    float e2 = __expf(v.z - m), e3 = __expf(v.w - m);
    float4 e = {e0, e1, e2, e3};
    *reinterpret_cast<float4*>(q + i * 4) = e;
    s += e0 + e1 + e2 + e3;
  }
#pragma unroll
  for (int o = 32; o > 0; o >>= 1) s += __shfl_xor(s, o);
  if (lane == 0) reds[w] = s;
  __syncthreads();
  float inv = 1.0f / (reds[0] + reds[1] + reds[2] + reds[3]);
  for (int i = tid; i < 250; i += 256) {
    float4 e = *reinterpret_cast<const float4*>(q + i * 4);
    e.x *= inv; e.y *= inv; e.z *= inv; e.w *= inv;
    *reinterpret_cast<float4*>(q + i * 4) = e;
  }
}

extern "C" void kernel_launch(void* const* d_in, const int* in_sizes, int n_in,
                              void* d_out, int out_size, void* d_ws, size_t ws_size,
                              hipStream_t stream) {
  const float* x = (const float*)d_in[0];
  const float* W_in = (const float*)d_in[1];
  const float* b_in = (const float*)d_in[2];
  const float* W1 = (const float*)d_in[3];
  const float* b1 = (const float*)d_in[4];
  const float* W2 = (const float*)d_in[5];
  const float* b2 = (const float*)d_in[6];
  const float* W_out = (const float*)d_in[7];
  const float* b_out = (const float*)d_in[8];
  float* out = (float*)d_out;

  const size_t Bm = 2048, U = 1024;
  char* ws = (char*)d_ws;
  size_t off = 0;
  auto alloc = [&](size_t bytes) -> void* {
    void* p = ws + off;
    off += (bytes + 255) & ~(size_t)255;
    return p;
  };
  unsigned short* xb = (unsigned short*)alloc(Bm * U * 2);
  unsigned short* winb = (unsigned short*)alloc((size_t)M1 * 2);
  unsigned short* wb = (unsigned short*)alloc(2 * (size_t)M1 * 2);    // W1,W2
  unsigned short* wtb = (unsigned short*)alloc(2 * (size_t)M1 * 2);   // W1^T,W2^T
  unsigned short* qb = (unsigned short*)alloc(2 * (size_t)M1 * 2);    // Q1,Q2
  unsigned short* a1b = (unsigned short*)alloc((size_t)M1 * 2);       // W1@Q1
  unsigned short* a2b = (unsigned short*)alloc((size_t)M1 * 2);       // W2@Q2
  unsigned short* bcat = (unsigned short*)alloc(2 * (size_t)M1 * 2);  // [Q1 ; W2^T] 1024x2048
  unsigned short* woutb = (unsigned short*)alloc((size_t)M1 * 2);
  float* boutp = (float*)alloc(U * 4);
  unsigned short* zb0 = (unsigned short*)alloc(Bm * U * 2);           // r1u bf16
  unsigned short* zcat = (unsigned short*)alloc(Bm * 2 * U * 2);      // [b1v | 0.1 r2u]
  unsigned short* zb2 = (unsigned short*)alloc(Bm * U * 2);           // b2v
  unsigned short* zb3 = (unsigned short*)alloc(Bm * U * 2);           // y2u
  float* r1u = (float*)alloc(Bm * U * 4);
  float* th = (float*)alloc(Bm * U * 4);
  float* r2u = (float*)alloc(Bm * U * 4);
  float* lgts = (float*)alloc(Bm * U * 4);

  k_prep<<<6145, 256, 0, stream>>>(x, W_in, W1, W2, W_out, b_out,
                                   xb, winb, wb, wtb, woutb, boutp, bcat);
  k_D2<<<1024, 256, 0, stream>>>(xb, winb, wtb, b_in, b1, r1u, th, zb0, qb, bcat);
  k_D3<<<1024, 256, 0, stream>>>(wb, qb, zb0, wtb, th, a1b, a2b, zcat);
  k_D4<<<512, 256, 0, stream>>>(zcat, a1b, b2, r1u, r2u, zcat + 1024);
  k_D5<<<512, 256, 0, stream>>>(zcat, bcat, th, zb2);
  k_D6<<<512, 256, 0, stream>>>(zb2, a2b, r2u, zb3);
  k_D7<<<512, 256, 0, stream>>>(zb3, woutb, boutp, lgts);
  k_softmax<<<2048, 256, 0, stream>>>(lgts, out);
}

// Round 15
// 102.426 us; speedup vs baseline: 1.0906x; 1.0906x over previous
//
#include <hip/hip_runtime.h>

// ---------------------------------------------------------------------------
// TransNetSweepingExplRhs — R15 = R13 DAG + depth-2 pair pipeline (T3/T4).
//   h = x@W_in^T + b_in ; th = tanh(h); r1u = h + 0.1 b1
//   Q_i = I/11 - (0.01/121) W_i^T W_i   (symmetric);  A_i = W_i@Q_i
//   b1v = 11 th + 0.1 (r1u@W1)
//   r2u = r1u + 0.1 b2 - 0.1 NT(b1v, A1)
//   b2v = 10 th + [b1v | 0.1 r2u] @ [Q1 ; W2^T]   (K=2048)
//   y2u = r2u - 0.1 NT(b2v, A2)
//   logits = NT(y2u, Wout) + bout ; out = softmax
// GEMM: tile 64x128, 512 thr (8 waves 2x4, wave tile 32x32, 2 waves/SIMD),
// BK=64/kt, superphase=2kt, THREE pair-buffers (144KB LDS, 1 block/CU).
// Iter s: vmcnt(6) [pair s+1 stays in flight] -> barrier -> STGP(s+2) ->
// CMP pair s. Loads get ~2 superphases of cover; vmcnt(0) only last iter.
// Rotation swizzle both sides; setprio around MFMA. Same K-order as R13 ->
// bit-identical output. XCD map: per-XCD <=2MB (K=1024) / 4MB (K=2048).
// ---------------------------------------------------------------------------

typedef short bf16x8 __attribute__((ext_vector_type(8)));
typedef float f32x4 __attribute__((ext_vector_type(4)));

#define M1 1048576

__device__ __forceinline__ unsigned short f2b(float f) {
  union { float f; unsigned int u; } v; v.f = f;
  unsigned int u = v.u;
  return (unsigned short)((u + 0x7FFFu + ((u >> 16) & 1u)) >> 16);
}

__device__ __forceinline__ void gload16(const void* g, void* l) {
  __builtin_amdgcn_global_load_lds(
      (const __attribute__((address_space(1))) unsigned int*)g,
      (__attribute__((address_space(3))) unsigned int*)l, 16, 0, 0);
}

// C[m,n] = sum_k A[m,k]*B[n,k]; tile 64(M)x128(N) at (bx,by); K = NKT*64.
// 512 threads. Staging per kt: A 1 load/thread, B 2 loads/thread.
// LDS per kt-slot: A rows[64]x8 chunks (slot (c+r)&7), B rows[128] same.
template <int MODE, int NKT>
__device__ __forceinline__ void gemm128(
    const unsigned short* __restrict__ A, int lda,
    const unsigned short* __restrict__ B, int ldb,
    int bx, int by,
    const float* bias0, const float* bias1, const float* src0,
    float* dstf0, float* dstf1,
    unsigned short* dstbf, int ldc, unsigned short* dstbf2,
    short (*As)[4096], short (*Bs)[8192]) {
  const int tid = threadIdx.x;
  const int lane = tid & 63;
  const int wid = tid >> 6;  // 0..7
  const int wr = wid >> 2;   // row half (32 rows)
  const int wc = wid & 3;    // col quarter (32 cols)
  const int m0 = bx * 64;
  const int n0 = by * 128;
  const int l15 = lane & 15;
  const int kb = lane >> 4;

  const int sr = tid >> 3;                  // 0..63
  const int sg = ((tid & 7) - sr) & 7;      // pre-swizzled source chunk
  const unsigned short* Asrc = A + (size_t)(m0 + sr) * lda + sg * 8;
  const unsigned short* Bsrc0 = B + (size_t)(n0 + sr) * ldb + sg * 8;
  const unsigned short* Bsrc1 = Bsrc0 + (size_t)64 * ldb;  // 64 = 0 mod 8: same swizzle
  const int od = tid * 8;

  f32x4 acc[2][2];
#pragma unroll
  for (int f = 0; f < 2; ++f)
#pragma unroll
    for (int g = 0; g < 2; ++g) acc[f][g] = (f32x4){0.f, 0.f, 0.f, 0.f};

  // pair p occupies kt-slots (p%3)*2 and (p%3)*2+1
#define STGP(p)                                                 \
  do {                                                          \
    _Pragma("unroll") for (int q = 0; q < 2; ++q) {             \
      const int kt = 2 * (p) + q;                               \
      const int sl = ((p) % 3) * 2 + q;                         \
      gload16(Asrc + kt * 64, &As[sl][od]);                     \
      gload16(Bsrc0 + kt * 64, &Bs[sl][od]);                    \
      gload16(Bsrc1 + kt * 64, &Bs[sl][4096 + od]);             \
    }                                                           \
  } while (0)

#define CMP(kt, sl)                                                            \
  do {                                                                         \
    _Pragma("unroll") for (int ks = 0; ks < 2; ++ks) {                         \
      bf16x8 av[2], bv[2];                                                     \
      _Pragma("unroll") for (int f = 0; f < 2; ++f) {                          \
        const int ra = wr * 32 + f * 16 + l15;                                 \
        const int qa = (ks * 4 + kb + l15) & 7;                                \
        av[f] = *reinterpret_cast<const bf16x8*>(&As[sl][ra * 64 + qa * 8]);   \
      }                                                                        \
      _Pragma("unroll") for (int g = 0; g < 2; ++g) {                          \
        const int rb = wc * 32 + g * 16 + l15;                                 \
        const int qb2 = (ks * 4 + kb + l15) & 7;                               \
        bv[g] = *reinterpret_cast<const bf16x8*>(&Bs[sl][rb * 64 + qb2 * 8]);  \
      }                                                                        \
      _Pragma("unroll") for (int f = 0; f < 2; ++f)                            \
          _Pragma("unroll") for (int g = 0; g < 2; ++g)                        \
              acc[f][g] = __builtin_amdgcn_mfma_f32_16x16x32_bf16(             \
                  av[f], bv[g], acc[f][g], 0, 0, 0);                           \
    }                                                                          \
  } while (0)

  constexpr int NP = NKT / 2;
  STGP(0);
  STGP(1);

#pragma unroll
  for (int s = 0; s < NP; ++s) {
    if (s + 1 < NP) {
      asm volatile("s_waitcnt vmcnt(6)" ::: "memory");
    } else {
      asm volatile("s_waitcnt vmcnt(0)" ::: "memory");
    }
    __builtin_amdgcn_sched_barrier(0);
    __builtin_amdgcn_s_barrier();
    __builtin_amdgcn_sched_barrier(0);
    if (s + 2 < NP) STGP(s + 2);
    const int sb = (s % 3) * 2;
    __builtin_amdgcn_s_setprio(1);
    CMP(2 * s, sb);
    CMP(2 * s + 1, sb + 1);
    __builtin_amdgcn_s_setprio(0);
  }
#undef STGP
#undef CMP

  // epilogue: C/D col = lane&15, row = (lane>>4)*4 + j
#pragma unroll
  for (int f = 0; f < 2; ++f) {
#pragma unroll
    for (int g = 0; g < 2; ++g) {
#pragma unroll
      for (int j = 0; j < 4; ++j) {
        int m = m0 + wr * 32 + f * 16 + kb * 4 + j;
        int n = n0 + wc * 32 + g * 16 + l15;
        size_t fidx = (size_t)m * 1024 + n;
        size_t cidx = (size_t)m * ldc + n;
        float v = acc[f][g][j];
        if (MODE == 0) {                  // plain bf16 (A1/A2)
          dstbf[cidx] = f2b(v);
        } else if (MODE == 1) {           // h-stage
          float h = v + bias0[n];
          float thv = tanhf(h);
          float r = h + 0.1f * bias1[n];
          dstf0[fidx] = r;
          dstf1[fidx] = thv;
          dstbf[cidx] = f2b(r);
        } else if (MODE == 2) {           // b1v = 11 th + 0.1 c1 -> zcat lo
          dstbf[cidx] = f2b(11.0f * src0[fidx] + 0.1f * v);
        } else if (MODE == 4) {           // r2u; store 0.1*r2u bf16 -> zcat hi
          float r = src0[fidx] + 0.1f * bias0[n] - 0.1f * v;
          dstf0[fidx] = r;
          dstbf[cidx] = f2b(0.1f * r);
        } else if (MODE == 5) {           // b2v = 10 th + v
          dstbf[cidx] = f2b(10.0f * src0[fidx] + v);
        } else if (MODE == 7) {           // y2u = r2u - 0.1 v
          dstbf[cidx] = f2b(src0[fidx] - 0.1f * v);
        } else if (MODE == 8) {           // logits
          dstf0[fidx] = v + bias0[n];
        } else {                          // MODE 9: Q = I/11 - (0.01/121) P
          float q = (m == n ? (1.0f / 11.0f) : 0.0f) - (0.01f / 121.0f) * v;
          unsigned short qq = f2b(q);
          dstbf[cidx] = qq;
          if (dstbf2) dstbf2[(size_t)m * 2048 + n] = qq;  // bcat lo (Q1)
        }
      }
    }
  }
}

// chain map: 32bx x 8by grid, XCD x owns 8bx x 4by  (<=2MB K=1024, 4MB K=2048)
__device__ __forceinline__ void mapc(int b, int& bx, int& by) {
  const int x = b & 7;
  const int j = b >> 3;  // 0..31
  bx = ((x & 3) << 3) | (j & 7);
  by = ((x >> 2) << 2) | (j >> 3);
}

// D2: G0 (h-stage, blocks 0..255) + QG (Q1,Q2, blocks 256..511)
__global__ __launch_bounds__(512) void k_D2(
    const unsigned short* __restrict__ xb, const unsigned short* __restrict__ winb,
    const unsigned short* __restrict__ wtb,
    const float* __restrict__ b_in, const float* __restrict__ b1,
    float* __restrict__ r1u, float* __restrict__ th,
    unsigned short* __restrict__ zb0, unsigned short* __restrict__ qb,
    unsigned short* __restrict__ bcat) {
  __shared__ short As[6][4096];
  __shared__ short Bs[6][8192];
  const int b = blockIdx.x;
  int bx, by;
  if (b < 256) {
    mapc(b, bx, by);
    gemm128<1, 16>(xb, 1024, winb, 1024, bx, by, b_in, b1, nullptr,
                   r1u, th, zb0, 1024, nullptr, As, Bs);
  } else {
    int r = b - 256;
    const int z = r >> 7;
    r &= 127;
    const int qbx = r & 15;   // 0..15 (1024/64)
    const int qby = r >> 4;   // 0..7  (1024/128)
    const unsigned short* wt = wtb + (size_t)z * M1;
    gemm128<9, 16>(wt, 1024, wt, 1024, qbx, qby, nullptr, nullptr, nullptr,
                   nullptr, nullptr, qb + (size_t)z * M1, 1024,
                   z == 0 ? bcat : nullptr, As, Bs);
  }
}

// D3: A1/A2 (0..255), b1v (256..511)
__global__ __launch_bounds__(512) void k_D3(
    const unsigned short* __restrict__ wb, const unsigned short* __restrict__ qb,
    const unsigned short* __restrict__ zb0, const unsigned short* __restrict__ wtb,
    const float* __restrict__ th,
    unsigned short* __restrict__ a1b, unsigned short* __restrict__ a2b,
    unsigned short* __restrict__ zcat) {
  __shared__ short As[6][4096];
  __shared__ short Bs[6][8192];
  const int b = blockIdx.x;
  if (b < 256) {
    const int z = b >> 7;
    const int r = b & 127;
    const int bx = r & 15;
    const int by = r >> 4;
    gemm128<0, 16>(wb + (size_t)z * M1, 1024, qb + (size_t)z * M1, 1024, bx, by,
                   nullptr, nullptr, nullptr, nullptr, nullptr,
                   z == 0 ? a1b : a2b, 1024, nullptr, As, Bs);
  } else {
    int bx, by;
    mapc(b - 256, bx, by);
    gemm128<2, 16>(zb0, 1024, wtb, 1024, bx, by, nullptr, nullptr, th,
                   nullptr, nullptr, zcat, 2048, nullptr, As, Bs);
  }
}

// D4: r2u = r1u + 0.1 b2 - 0.1 NT(b1v, A1)
__global__ __launch_bounds__(512) void k_D4(
    const unsigned short* __restrict__ zcat, const unsigned short* __restrict__ a1b,
    const float* __restrict__ b2, const float* __restrict__ r1u,
    float* __restrict__ r2u, unsigned short* __restrict__ zcat_hi) {
  __shared__ short As[6][4096];
  __shared__ short Bs[6][8192];
  int bx, by;
  mapc(blockIdx.x, bx, by);
  gemm128<4, 16>(zcat, 2048, a1b, 1024, bx, by, b2, nullptr, r1u,
                 r2u, nullptr, zcat_hi, 2048, nullptr, As, Bs);
}

// D5: b2v = 10 th + [b1v | 0.1 r2u] @ bcat  (K=2048)
__global__ __launch_bounds__(512) void k_D5(
    const unsigned short* __restrict__ zcat, const unsigned short* __restrict__ bcat,
    const float* __restrict__ th, unsigned short* __restrict__ zb2) {
  __shared__ short As[6][4096];
  __shared__ short Bs[6][8192];
  int bx, by;
  mapc(blockIdx.x, bx, by);
  gemm128<5, 32>(zcat, 2048, bcat, 2048, bx, by, nullptr, nullptr, th,
                 nullptr, nullptr, zb2, 1024, nullptr, As, Bs);
}

// D6: y2u = r2u - 0.1 NT(b2v, A2)
__global__ __launch_bounds__(512) void k_D6(
    const unsigned short* __restrict__ zb2, const unsigned short* __restrict__ a2b,
    const float* __restrict__ r2u, unsigned short* __restrict__ zb3) {
  __shared__ short As[6][4096];
  __shared__ short Bs[6][8192];
  int bx, by;
  mapc(blockIdx.x, bx, by);
  gemm128<7, 16>(zb2, 1024, a2b, 1024, bx, by, nullptr, nullptr, r2u,
                 nullptr, nullptr, zb3, 1024, nullptr, As, Bs);
}

// D7: logits = NT(y2u, Wout_pad) + bout
__global__ __launch_bounds__(512) void k_D7(
    const unsigned short* __restrict__ zb3, const unsigned short* __restrict__ woutb,
    const float* __restrict__ boutp, float* __restrict__ lgts) {
  __shared__ short As[6][4096];
  __shared__ short Bs[6][8192];
  int bx, by;
  mapc(blockIdx.x, bx, by);
  gemm128<8, 16>(zb3, 1024, woutb, 1024, bx, by, boutp, nullptr, nullptr,
                 lgts, nullptr, nullptr, 1024, nullptr, As, Bs);
}

// prep: W1/W2 bf16+transpose (0..2047; W2 also fills bcat hi), x (2048..4095),
// W_in (4096..5119), W_out padded (5120..6143), b_out (6144)
__global__ __launch_bounds__(256) void k_prep(
    const float* __restrict__ x, const float* __restrict__ Win,
    const float* __restrict__ W1, const float* __restrict__ W2,
    const float* __restrict__ Wout, const float* __restrict__ bout,
    unsigned short* __restrict__ xb, unsigned short* __restrict__ winb,
    unsigned short* __restrict__ wb, unsigned short* __restrict__ wtb,
    unsigned short* __restrict__ woutb, float* __restrict__ boutp,
    unsigned short* __restrict__ bcat) {
  __shared__ float tile[32][33];
  const int b = blockIdx.x;
  const int tid = threadIdx.x;
  if (b < 2048) {
    const int isW2 = (b >> 10) & 1;
    const float* W = isW2 ? W2 : W1;
    unsigned short* Wb = wb + ((size_t)isW2 << 20);
    unsigned short* WTb = wtb + ((size_t)isW2 << 20);
    const int rem = b & 1023;
    const int tbx = rem & 31, tby = rem >> 5;
    const int tx = tid & 31, ty = tid >> 5;
#pragma unroll
    for (int i = ty; i < 32; i += 8) {
      float v = W[(size_t)(tby * 32 + i) * 1024 + tbx * 32 + tx];
      tile[i][tx] = v;
      Wb[(size_t)(tby * 32 + i) * 1024 + tbx * 32 + tx] = f2b(v);
    }
    __syncthreads();
#pragma unroll
    for (int i = ty; i < 32; i += 8) {
      unsigned short t2 = f2b(tile[tx][i]);
      int rr = tbx * 32 + i, cc = tby * 32 + tx;
      WTb[(size_t)rr * 1024 + cc] = t2;
      if (isW2) bcat[(size_t)rr * 2048 + 1024 + cc] = t2;  // bcat hi = W2^T
    }
  } else if (b < 4096) {
    int i = (b - 2048) * 256 + tid;
    float4 v = ((const float4*)x)[i];
    ((ushort4*)xb)[i] = (ushort4){f2b(v.x), f2b(v.y), f2b(v.z), f2b(v.w)};
  } else if (b < 5120) {
    int i = (b - 4096) * 256 + tid;
    float4 v = ((const float4*)Win)[i];
    ((ushort4*)winb)[i] = (ushort4){f2b(v.x), f2b(v.y), f2b(v.z), f2b(v.w)};
  } else if (b < 6144) {
    int i = (b - 5120) * 256 + tid;
    ushort4 o = (ushort4){0, 0, 0, 0};
    if ((i >> 8) < 1000) {
      float4 v = ((const float4*)Wout)[i];
      o = (ushort4){f2b(v.x), f2b(v.y), f2b(v.z), f2b(v.w)};
    }
    ((ushort4*)woutb)[i] = o;
  } else {
    for (int j = tid; j < 1024; j += 256) boutp[j] = (j < 1000) ? bout[j] : 0.0f;
  }
}

// row softmax over first 1000 cols of 2048x1024 logits -> 2048x1000
__global__ __launch_bounds__(256) void k_softmax(const float* __restrict__ lg,
                                                 float* __restrict__ out) {
  const int r = blockIdx.x;
  const float4* p4 = (const float4*)(lg + (size_t)r * 1024);
  float* q = out + (size_t)r * 1000;
  const int tid = threadIdx.x;
  const int lane = tid & 63;
  const int w = tid >> 6;
  __shared__ float redm[4];
  __shared__ float reds[4];
  float m = -3.0e38f;
  for (int i = tid; i < 250; i += 256) {
    float4 v = p4[i];
    m = fmaxf(fmaxf(fmaxf(m, v.x), fmaxf(v.y, v.z)), v.w);
  }
#pragma unroll
  for (int o = 32; o > 0; o >>= 1) m = fmaxf(m, __shfl_xor(m, o));
  if (lane == 0) redm[w] = m;
  __syncthreads();
  m = fmaxf(fmaxf(redm[0], redm[1]), fmaxf(redm[2], redm[3]));
  float s = 0.0f;
  for (int i = tid; i < 250; i += 256) {
    float4 v = p4[i];
    float e0 = __expf(v.x - m), e1 = __expf(v.y - m);
    float e2 = __expf(v.z - m), e3 = __expf(v.w - m);
    float4 e = {e0, e1, e2, e3};
    *reinterpret_cast<float4*>(q + i * 4) = e;
    s += e0 + e1 + e2 + e3;
  }
#pragma unroll
  for (int o = 32; o > 0; o >>= 1) s += __shfl_xor(s, o);
  if (lane == 0) reds[w] = s;
  __syncthreads();
  float inv = 1.0f / (reds[0] + reds[1] + reds[2] + reds[3]);
  for (int i = tid; i < 250; i += 256) {
    float4 e = *reinterpret_cast<const float4*>(q + i * 4);
    e.x *= inv; e.y *= inv; e.z *= inv; e.w *= inv;
    *reinterpret_cast<float4*>(q + i * 4) = e;
  }
}

extern "C" void kernel_launch(void* const* d_in, const int* in_sizes, int n_in,
                              void* d_out, int out_size, void* d_ws, size_t ws_size,
                              hipStream_t stream) {
  const float* x = (const float*)d_in[0];
  const float* W_in = (const float*)d_in[1];
  const float* b_in = (const float*)d_in[2];
  const float* W1 = (const float*)d_in[3];
  const float* b1 = (const float*)d_in[4];
  const float* W2 = (const float*)d_in[5];
  const float* b2 = (const float*)d_in[6];
  const float* W_out = (const float*)d_in[7];
  const float* b_out = (const float*)d_in[8];
  float* out = (float*)d_out;

  const size_t Bm = 2048, U = 1024;
  char* ws = (char*)d_ws;
  size_t off = 0;
  auto alloc = [&](size_t bytes) -> void* {
    void* p = ws + off;
    off += (bytes + 255) & ~(size_t)255;
    return p;
  };
  unsigned short* xb = (unsigned short*)alloc(Bm * U * 2);
  unsigned short* winb = (unsigned short*)alloc((size_t)M1 * 2);
  unsigned short* wb = (unsigned short*)alloc(2 * (size_t)M1 * 2);    // W1,W2
  unsigned short* wtb = (unsigned short*)alloc(2 * (size_t)M1 * 2);   // W1^T,W2^T
  unsigned short* qb = (unsigned short*)alloc(2 * (size_t)M1 * 2);    // Q1,Q2
  unsigned short* a1b = (unsigned short*)alloc((size_t)M1 * 2);       // W1@Q1
  unsigned short* a2b = (unsigned short*)alloc((size_t)M1 * 2);       // W2@Q2
  unsigned short* bcat = (unsigned short*)alloc(2 * (size_t)M1 * 2);  // [Q1 ; W2^T] 1024x2048
  unsigned short* woutb = (unsigned short*)alloc((size_t)M1 * 2);
  float* boutp = (float*)alloc(U * 4);
  unsigned short* zb0 = (unsigned short*)alloc(Bm * U * 2);           // r1u bf16
  unsigned short* zcat = (unsigned short*)alloc(Bm * 2 * U * 2);      // [b1v | 0.1 r2u]
  unsigned short* zb2 = (unsigned short*)alloc(Bm * U * 2);           // b2v
  unsigned short* zb3 = (unsigned short*)alloc(Bm * U * 2);           // y2u
  float* r1u = (float*)alloc(Bm * U * 4);
  float* th = (float*)alloc(Bm * U * 4);
  float* r2u = (float*)alloc(Bm * U * 4);
  float* lgts = (float*)alloc(Bm * U * 4);

  k_prep<<<6145, 256, 0, stream>>>(x, W_in, W1, W2, W_out, b_out,
                                   xb, winb, wb, wtb, woutb, boutp, bcat);
  k_D2<<<512, 512, 0, stream>>>(xb, winb, wtb, b_in, b1, r1u, th, zb0, qb, bcat);
  k_D3<<<512, 512, 0, stream>>>(wb, qb, zb0, wtb, th, a1b, a2b, zcat);
  k_D4<<<256, 512, 0, stream>>>(zcat, a1b, b2, r1u, r2u, zcat + 1024);
  k_D5<<<256, 512, 0, stream>>>(zcat, bcat, th, zb2);
  k_D6<<<256, 512, 0, stream>>>(zb2, a2b, r2u, zb3);
  k_D7<<<256, 512, 0, stream>>>(zb3, woutb, boutp, lgts);
  k_softmax<<<2048, 256, 0, stream>>>(lgts, out);
}